// Round 6
// baseline (259.696 us; speedup 1.0000x reference)
//
#include <hip/hip_runtime.h>
#include <hip/hip_bf16.h>

#define NN 512      // nodes per graph
#define NE 8192     // edges per graph
#define NG 128      // graphs (B*G)
#define FH 128      // feature/hidden dim
#define APITCH 68   // A-chunk float pitch: 272 B row (16B-aligned), bank stride 4 -> 2-way (free)
#define XPITCH 136
#define CAP 512     // bucket capacity (mean 256, sigma~16 -> 16 sigma headroom)
#define BN_EPS 1e-5f

typedef __attribute__((ext_vector_type(8))) short s8v;            // 8 bf16 = 4 VGPRs
typedef __attribute__((ext_vector_type(4))) float f4v;            // MFMA C/D
typedef __attribute__((ext_vector_type(4))) unsigned short us4v;  // native ushort4
typedef __attribute__((ext_vector_type(4))) unsigned int u4v;

__device__ inline unsigned short f2bf(float x) {   // RNE fp32 -> bf16 bits
    unsigned u = __float_as_uint(x);
    unsigned r = (u + 0x7fffu + ((u >> 16) & 1u)) >> 16;
    return (unsigned short)r;
}
__device__ inline float bf2f(unsigned short h) { return __uint_as_float(((unsigned)h) << 16); }

// pack hi16(f1):hi16(f0) -> one u32 (exact bf16 for integer-valued floats < 256)
__device__ inline unsigned bfpack(int f1bits, int f0bits) {
    return __builtin_amdgcn_perm((unsigned)f1bits, (unsigned)f0bits, 0x07060302u);
}

// ---------------- K0 "prep": zero deg/fill counters; 2 blocks pack W0/W1 ----------------
__global__ __launch_bounds__(1024) void k_prep(int* __restrict__ degO,
                                               int* __restrict__ degI,
                                               int* __restrict__ fill,
                                               const float* __restrict__ W0,
                                               const float* __restrict__ W1,
                                               unsigned short* __restrict__ WP) {
    int b = blockIdx.x;
    int tid = threadIdx.x;
    if (b < 64) {
        // zero degO (64K ints), degI (64K), fill (4K) = 132K ints = 33024 int4
        int4 z = {0, 0, 0, 0};
        int idx = b * 1024 + tid;                     // 0..65535
        if (idx < NG * NN / 4) { ((int4*)degO)[idx] = z; ((int4*)degI)[idx] = z; }
        if (idx < NG * 32 / 4) ((int4*)fill)[idx] = z;
        return;
    }
    int which = b - 64;
    const float* W = which ? W1 : W0;
    for (int task = tid; task < 2048; task += 1024) {
        int t = task >> 6;            // 0..31  (nt*4+kk)
        int lane = task & 63;
        int nt = t >> 2, kk = t & 3;
        int n = nt * 16 + (lane & 15);
        int k0 = kk * 32 + (lane >> 4) * 8;
        unsigned short* dh = WP + ((size_t)which * 2 + 0) * 16384 + ((size_t)t * 64 + lane) * 8;
        unsigned short* dl = WP + ((size_t)which * 2 + 1) * 16384 + ((size_t)t * 64 + lane) * 8;
#pragma unroll
        for (int j = 0; j < 8; j++) {
            float v = W[(size_t)(k0 + j) * FH + n];
            unsigned short h = f2bf(v);
            dh[j] = h;
            dl[j] = f2bf(v - bf2f(h));
        }
    }
}

// ---------------- K1 "edges": degrees + fixed-capacity bucket scatter (no sort, no scan) ----------------
// bucket = (dstblk128, srcchunk64); payload = (d&127)<<6 | (s&63).
__global__ __launch_bounds__(1024) void k_edges(const int* __restrict__ edges,
                                                int* __restrict__ degO,
                                                int* __restrict__ degI,
                                                int* __restrict__ fill,
                                                unsigned short* __restrict__ epk) {
    int g = blockIdx.x;
    int q = blockIdx.y;            // 0..3, 2048 edges each
    int t = threadIdx.x;
    const int* src = edges + (size_t)g * 2 * NE + q * 2048;
    const int* dst = src + NE;
    int2 sp = ((const int2*)src)[t];
    int2 dp = ((const int2*)dst)[t];
    int* dgO = degO + g * NN;
    int* dgI = degI + g * NN;
    int* fl  = fill + g * 32;
    unsigned short* ep = epk + (size_t)g * 32 * CAP;

    atomicAdd(&dgO[sp.x], 1);
    atomicAdd(&dgI[dp.x], 1);
    int b0 = ((dp.x >> 7) << 3) | (sp.x >> 6);
    int s0 = atomicAdd(&fl[b0], 1);
    if (s0 < CAP) ep[b0 * CAP + s0] = (unsigned short)(((dp.x & 127) << 6) | (sp.x & 63));

    atomicAdd(&dgO[sp.y], 1);
    atomicAdd(&dgI[dp.y], 1);
    int b1 = ((dp.y >> 7) << 3) | (sp.y >> 6);
    int s1 = atomicAdd(&fl[b1], 1);
    if (s1 < CAP) ep[b1 * CAP + s1] = (unsigned short)(((dp.y & 127) << 6) | (sp.y & 63));
}

// ---------------- K2: Y1f = pack_Bfrag((feats @ W0) * rs_out)  (hi/lo split, 3 MFMA) ----------------
__global__ __launch_bounds__(256) void k_gemm_f32(const float* __restrict__ X,
                                                  const unsigned short* __restrict__ WPh,
                                                  const unsigned short* __restrict__ WPl,
                                                  const int* __restrict__ degO,
                                                  unsigned short* __restrict__ Yf) {
    __shared__ unsigned short xh[64 * XPITCH];   // 17 KB
    __shared__ unsigned short xl[64 * XPITCH];   // 17 KB
    int tid = threadIdx.x;
    int sb = blockIdx.y;
    size_t r0 = (size_t)blockIdx.x * NN + (size_t)sb * 64;

    const float4* Xv = (const float4*)(X + r0 * FH);
#pragma unroll
    for (int i = 0; i < 8; i++) {
        int u = tid + i * 256;                 // 2048 float4 = 64x128
        int row = u >> 5, c4 = (u & 31) * 4;
        float4 v = Xv[u];
        int off = row * XPITCH + c4;
        unsigned short h0 = f2bf(v.x), h1 = f2bf(v.y), h2 = f2bf(v.z), h3 = f2bf(v.w);
        us4v hv, lv;
        hv.x = h0; hv.y = h1; hv.z = h2; hv.w = h3;
        lv.x = f2bf(v.x - bf2f(h0));
        lv.y = f2bf(v.y - bf2f(h1));
        lv.z = f2bf(v.z - bf2f(h2));
        lv.w = f2bf(v.w - bf2f(h3));
        *(us4v*)(xh + off) = hv;
        *(us4v*)(xl + off) = lv;
    }
    __syncthreads();

    int lane = tid & 63, w = tid >> 6;
    int quad = lane >> 4, m = lane & 15;
    int arow = w * 16 + m;

    f4v acc[8];
#pragma unroll
    for (int nt = 0; nt < 8; nt++) acc[nt] = (f4v){0.f, 0.f, 0.f, 0.f};

#pragma unroll
    for (int kk = 0; kk < 4; kk++) {
        s8v ah = *(const s8v*)&xh[arow * XPITCH + kk * 32 + quad * 8];
        s8v al = *(const s8v*)&xl[arow * XPITCH + kk * 32 + quad * 8];
#pragma unroll
        for (int nt = 0; nt < 8; nt++) {
            s8v bh = *(const s8v*)(WPh + ((size_t)(nt * 4 + kk) * 64 + lane) * 8);
            s8v bl = *(const s8v*)(WPl + ((size_t)(nt * 4 + kk) * 64 + lane) * 8);
            acc[nt] = __builtin_amdgcn_mfma_f32_16x16x32_bf16(ah, bh, acc[nt], 0, 0, 0);
            acc[nt] = __builtin_amdgcn_mfma_f32_16x16x32_bf16(al, bh, acc[nt], 0, 0, 0);
            acc[nt] = __builtin_amdgcn_mfma_f32_16x16x32_bf16(ah, bl, acc[nt], 0, 0, 0);
        }
    }

    int orow = w * 16 + quad * 4;
    int4 dg = *(const int4*)(degO + r0 + orow);
    float4 rsv;
    rsv.x = rsqrtf((float)max(dg.x, 1));
    rsv.y = rsqrtf((float)max(dg.y, 1));
    rsv.z = rsqrtf((float)max(dg.z, 1));
    rsv.w = rsqrtf((float)max(dg.w, 1));
    int tag = (w * 2 + (quad >> 1)) & 3;
    int kko = sb * 2 + (w >> 1);
    int j0  = (quad & 1) * 4;
    unsigned short* of = Yf + (size_t)blockIdx.x * (NN * FH);
#pragma unroll
    for (int nt = 0; nt < 8; nt++) {
        us4v v;
        v.x = f2bf(acc[nt][0] * rsv.x);
        v.y = f2bf(acc[nt][1] * rsv.y);
        v.z = f2bf(acc[nt][2] * rsv.z);
        v.w = f2bf(acc[nt][3] * rsv.w);
        *(us4v*)(of + (((size_t)kko * 8 + nt) * 64 + (m + 16 * tag)) * 8 + j0) = v;
    }
}

// ---------------- K3: FUSED dense-A MFMA aggregation (128-row dst tile, bucket counts) + gemm2 -> Y2f ----------------
__global__ __launch_bounds__(1024) void k_fused(const unsigned short* __restrict__ Y1f,
                                                const int* __restrict__ fill,
                                                const unsigned short* __restrict__ epk,
                                                const int* __restrict__ degI,
                                                const int* __restrict__ degO,
                                                const float* __restrict__ bias,
                                                const unsigned short* __restrict__ WPh,
                                                const unsigned short* __restrict__ WPl,
                                                unsigned short* __restrict__ Y2f) {
    int g  = blockIdx.x;
    int sb = blockIdx.y;   // 0..3
    int tid = threadIdx.x;
    int lane = tid & 63, w16 = tid >> 6;   // 16 waves
    int quad = lane >> 4, m = lane & 15;
    int mt = w16 & 7, nh = w16 >> 3;
    int base = sb * 128;

    __shared__ float Af[128 * APITCH];            // 34816 B; hs aliases this after agg
    __shared__ unsigned short Bs[2 * 8 * 64 * 8]; // 16384 B B-chunk
    unsigned short* hs = (unsigned short*)Af;     // 128*XPITCH*2 = 34816 B exactly
    __shared__ float rsin_s[128];
    __shared__ int cnt_s[8];

    const unsigned short* ep = epk + (size_t)g * 32 * CAP;
    const int4* Yi4 = (const int4*)(Y1f + (size_t)g * (NN * FH));
    int4* Bi4 = (int4*)Bs;

    // prologue: B[0] load issued immediately (1 int4/thread)
    int4 rB0 = Yi4[tid];

    if (tid < 128) rsin_s[tid] = rsqrtf((float)max(degI[g * NN + base + tid], 1));
    if (tid < 8)   cnt_s[tid] = min(fill[g * 32 + sb * 8 + tid], CAP);
    __syncthreads();

    f4v acc[4];
#pragma unroll
    for (int j = 0; j < 4; j++) acc[j] = (f4v){0.f, 0.f, 0.f, 0.f};

    for (int p = 0; p < 8; p++) {
        if (p) __syncthreads();             // prior pass's Af/Bs reads done
        float4 z4 = {0.f, 0.f, 0.f, 0.f};
        for (int i = tid; i < 128 * APITCH / 4; i += 1024) ((float4*)Af)[i] = z4;
        Bi4[tid] = rB0;                     // commit pass-p B-chunk
        __syncthreads();                    // zero + B visible
        int cnt = cnt_s[p];
        int eb = (sb * 8 + p) * CAP;
        for (int e = tid; e < cnt; e += 1024) {
            int v = ep[eb + e];
            atomicAdd(&Af[(v >> 6) * APITCH + (v & 63)], 1.0f);
        }
        __syncthreads();                    // A ready
        if (p < 7) rB0 = Yi4[(p + 1) * 1024 + tid];   // prefetch flies under MFMA
#pragma unroll
        for (int kkl = 0; kkl < 2; kkl++) {
            s8v bf[4];
#pragma unroll
            for (int j = 0; j < 4; j++)
                bf[j] = *(const s8v*)&Bs[((kkl * 8 + nh * 4 + j) * 64 + lane) * 8];
            const int4* ap = (const int4*)&Af[(mt * 16 + m) * APITCH + kkl * 32 + quad * 8];
            int4 a0 = ap[0];
            int4 a1 = ap[1];
            union { u4v u; s8v s; } cv;
            cv.u.x = bfpack(a0.y, a0.x);
            cv.u.y = bfpack(a0.w, a0.z);
            cv.u.z = bfpack(a1.y, a1.x);
            cv.u.w = bfpack(a1.w, a1.z);
            s8v af = cv.s;
#pragma unroll
            for (int j = 0; j < 4; j++)
                acc[j] = __builtin_amdgcn_mfma_f32_16x16x32_bf16(af, bf[j], acc[j], 0, 0, 0);
        }
    }
    __syncthreads();   // agg done; Af reusable as hs

    // ---- conv1 epilogue: h = relu(rs_in*agg + b0) -> hs (natural [row][feat]) ----
#pragma unroll
    for (int j = 0; j < 4; j++) {
        int feat = (nh * 4 + j) * 16 + m;
        float bv = bias[feat];
#pragma unroll
        for (int i = 0; i < 4; i++) {
            int r = mt * 16 + quad * 4 + i;
            float hv = fmaxf(fmaf(rsin_s[r], acc[j][i], bv), 0.f);
            hs[r * XPITCH + feat] = f2bf(hv);
        }
    }
    __syncthreads();

    // ---- gemm2: Y2 = (h @ W1) * rs_out, packed B-fragment output ----
    f4v acc2[4];
#pragma unroll
    for (int j = 0; j < 4; j++) acc2[j] = (f4v){0.f, 0.f, 0.f, 0.f};

#pragma unroll
    for (int kk = 0; kk < 4; kk++) {
        s8v ah = *(const s8v*)&hs[(mt * 16 + m) * XPITCH + kk * 32 + quad * 8];
#pragma unroll
        for (int j = 0; j < 4; j++) {
            int nt = nh * 4 + j;
            s8v bh = *(const s8v*)(WPh + ((size_t)(nt * 4 + kk) * 64 + lane) * 8);
            s8v bl = *(const s8v*)(WPl + ((size_t)(nt * 4 + kk) * 64 + lane) * 8);
            acc2[j] = __builtin_amdgcn_mfma_f32_16x16x32_bf16(ah, bh, acc2[j], 0, 0, 0);
            acc2[j] = __builtin_amdgcn_mfma_f32_16x16x32_bf16(ah, bl, acc2[j], 0, 0, 0);
        }
    }

    int orow = mt * 16 + quad * 4;
    int4 dg = *(const int4*)(degO + (size_t)g * NN + base + orow);
    float4 rsv;
    rsv.x = rsqrtf((float)max(dg.x, 1));
    rsv.y = rsqrtf((float)max(dg.y, 1));
    rsv.z = rsqrtf((float)max(dg.z, 1));
    rsv.w = rsqrtf((float)max(dg.w, 1));
    int tag = (mt & 1) * 2 + (quad >> 1);
    int kko = sb * 4 + (mt >> 1);
    int j0  = (quad & 1) * 4;
    unsigned short* of = Y2f + (size_t)g * (NN * FH);
#pragma unroll
    for (int j = 0; j < 4; j++) {
        int nt = nh * 4 + j;
        us4v v;
        v.x = f2bf(acc2[j][0] * rsv.x);
        v.y = f2bf(acc2[j][1] * rsv.y);
        v.z = f2bf(acc2[j][2] * rsv.z);
        v.w = f2bf(acc2[j][3] * rsv.w);
        *(us4v*)(of + (((size_t)kko * 8 + nt) * 64 + (m + 16 * tag)) * 8 + j0) = v;
    }
}

// ---------------- K4: dense-A MFMA aggregation (128-row tile, bucket counts) + relu + node-sum -> partial ----------------
__global__ __launch_bounds__(1024) void k_gather_mean(const unsigned short* __restrict__ Y2f,
                                                      const int* __restrict__ fill,
                                                      const unsigned short* __restrict__ epk,
                                                      const int* __restrict__ degI,
                                                      const float* __restrict__ bias,
                                                      float* __restrict__ partial) {
    int g  = blockIdx.x;
    int sb = blockIdx.y;   // 0..3
    int tid = threadIdx.x;
    int lane = tid & 63, w16 = tid >> 6;
    int quad = lane >> 4, m = lane & 15;
    int mt = w16 & 7, nh = w16 >> 3;
    int base = sb * 128;

    __shared__ float Af[128 * APITCH];            // 34816 B; red aliases this after agg
    __shared__ unsigned short Bs[2 * 8 * 64 * 8]; // 16384 B
    float* red = (float*)Af;                      // [16][64][4] = 16384 B
    __shared__ float rsin_s[128];
    __shared__ int cnt_s[8];

    const unsigned short* ep = epk + (size_t)g * 32 * CAP;
    const int4* Yi4 = (const int4*)(Y2f + (size_t)g * (NN * FH));
    int4* Bi4 = (int4*)Bs;

    int4 rB0 = Yi4[tid];

    if (tid < 128) rsin_s[tid] = rsqrtf((float)max(degI[g * NN + base + tid], 1));
    if (tid < 8)   cnt_s[tid] = min(fill[g * 32 + sb * 8 + tid], CAP);
    __syncthreads();

    f4v acc[4];
#pragma unroll
    for (int j = 0; j < 4; j++) acc[j] = (f4v){0.f, 0.f, 0.f, 0.f};

    for (int p = 0; p < 8; p++) {
        if (p) __syncthreads();
        float4 z4 = {0.f, 0.f, 0.f, 0.f};
        for (int i = tid; i < 128 * APITCH / 4; i += 1024) ((float4*)Af)[i] = z4;
        Bi4[tid] = rB0;
        __syncthreads();
        int cnt = cnt_s[p];
        int eb = (sb * 8 + p) * CAP;
        for (int e = tid; e < cnt; e += 1024) {
            int v = ep[eb + e];
            atomicAdd(&Af[(v >> 6) * APITCH + (v & 63)], 1.0f);
        }
        __syncthreads();
        if (p < 7) rB0 = Yi4[(p + 1) * 1024 + tid];
#pragma unroll
        for (int kkl = 0; kkl < 2; kkl++) {
            s8v bf[4];
#pragma unroll
            for (int j = 0; j < 4; j++)
                bf[j] = *(const s8v*)&Bs[((kkl * 8 + nh * 4 + j) * 64 + lane) * 8];
            const int4* ap = (const int4*)&Af[(mt * 16 + m) * APITCH + kkl * 32 + quad * 8];
            int4 a0 = ap[0];
            int4 a1 = ap[1];
            union { u4v u; s8v s; } cv;
            cv.u.x = bfpack(a0.y, a0.x);
            cv.u.y = bfpack(a0.w, a0.z);
            cv.u.z = bfpack(a1.y, a1.x);
            cv.u.w = bfpack(a1.w, a1.z);
            s8v af = cv.s;
#pragma unroll
            for (int j = 0; j < 4; j++)
                acc[j] = __builtin_amdgcn_mfma_f32_16x16x32_bf16(af, bf[j], acc[j], 0, 0, 0);
        }
    }
    __syncthreads();   // agg done; Af reusable as red

    // ---- epilogue: relu(rs_in*agg + b1) summed over this lane's 4 rows, per nt ----
#pragma unroll
    for (int j = 0; j < 4; j++) {
        int feat = (nh * 4 + j) * 16 + m;
        float bv = bias[feat];
        float s = 0.f;
#pragma unroll
        for (int i = 0; i < 4; i++) {
            int r = mt * 16 + quad * 4 + i;
            s += fmaxf(fmaf(rsin_s[r], acc[j][i], bv), 0.f);
        }
        red[(w16 * 64 + lane) * 4 + j] = s;
    }
    __syncthreads();
    if (tid < FH) {
        int f = tid;
        int nt = f >> 4, mm = f & 15;
        int nhh = nt >> 2, jj = nt & 3;
        float t = 0.f;
#pragma unroll
        for (int mtt = 0; mtt < 8; mtt++)
#pragma unroll
            for (int q = 0; q < 4; q++)
                t += red[(((nhh * 8 + mtt) * 64) + q * 16 + mm) * 4 + jj];
        partial[((size_t)g * 4 + sb) * FH + f] = t;
    }
}

// ---------------- K5: z = (sum partials)/512 @ Wt + bt; BN eval; relu ----------------
__global__ __launch_bounds__(128) void k_head(const float* __restrict__ partial,
                                              const float* __restrict__ Wt,
                                              const float* __restrict__ bt,
                                              const float* __restrict__ gamma,
                                              const float* __restrict__ beta,
                                              const float* __restrict__ rmean,
                                              const float* __restrict__ rvar,
                                              float* __restrict__ out) {
    int g = blockIdx.x;
    int j = threadIdx.x;
    __shared__ float e[FH];
    float acc4 = 0.f;
#pragma unroll
    for (int q = 0; q < 4; q++) acc4 += partial[((size_t)g * 4 + q) * FH + j];
    e[j] = acc4 * (1.0f / (float)NN);
    __syncthreads();
    float acc = bt[j];
#pragma unroll 8
    for (int k = 0; k < FH; k++) acc += e[k] * Wt[(size_t)k * FH + j];
    float z = gamma[j] * (acc - rmean[j]) * rsqrtf(rvar[j] + BN_EPS) + beta[j];
    out[g * FH + j] = fmaxf(z, 0.f);
}

extern "C" void kernel_launch(void* const* d_in, const int* in_sizes, int n_in,
                              void* d_out, int out_size, void* d_ws, size_t ws_size,
                              hipStream_t stream) {
    const float* feats = (const float*)d_in[0];
    const int*   edges = (const int*)d_in[1];
    const float* W0    = (const float*)d_in[2];
    const float* b0    = (const float*)d_in[3];
    const float* W1    = (const float*)d_in[4];
    const float* b1    = (const float*)d_in[5];
    const float* Wt    = (const float*)d_in[6];
    const float* bt    = (const float*)d_in[7];
    const float* gamma = (const float*)d_in[8];
    const float* beta  = (const float*)d_in[9];
    const float* rmean = (const float*)d_in[10];
    const float* rvar  = (const float*)d_in[11];
    float* out = (float*)d_out;

    // workspace layout
    char* w = (char*)d_ws;
    int* degO = (int*)w;   w += sizeof(int) * NG * NN;                     // 256 KB
    int* degI = (int*)w;   w += sizeof(int) * NG * NN;                     // 256 KB
    int* fillc = (int*)w;  w += sizeof(int) * NG * 32;                     // 16 KB
    unsigned short* epk = (unsigned short*)w; w += sizeof(unsigned short) * (size_t)NG * 32 * CAP; // 4 MB
    unsigned short* WP  = (unsigned short*)w; w += sizeof(unsigned short) * 4 * 16384;       // 128 KB
    unsigned short* Y1  = (unsigned short*)w; w += sizeof(unsigned short) * (size_t)NG * NN * FH; // 16 MB
    unsigned short* Y2  = (unsigned short*)w; w += sizeof(unsigned short) * (size_t)NG * NN * FH; // 16 MB
    float* partial = (float*)w;   w += sizeof(float) * NG * 4 * FH;

    unsigned short* WPh0 = WP;
    unsigned short* WPl0 = WP + 16384;
    unsigned short* WPh1 = WP + 32768;
    unsigned short* WPl1 = WP + 49152;

    // K0: zero counters + pack W0/W1
    k_prep<<<66, 1024, 0, stream>>>(degO, degI, fillc, W0, W1, WP);

    // K1: degrees + fixed-capacity bucket scatter (all CUs, no scan)
    k_edges<<<dim3(NG, 4), 1024, 0, stream>>>(edges, degO, degI, fillc, epk);

    // K2: conv1 gemm (feats -> Y1, B-fragment packed; rs_out from degO inline)
    k_gemm_f32<<<dim3(NG, 8), 256, 0, stream>>>(feats, WPh0, WPl0, degO, Y1);

    // K3: fused dense-A MFMA aggregation (128-row tiles) + conv2 gemm (Y1 -> Y2, packed)
    k_fused<<<dim3(NG, 4), 1024, 0, stream>>>(Y1, fillc, epk, degI, degO, b0, WPh1, WPl1, Y2);

    // K4: dense-A MFMA aggregation (128-row tiles, conv2) + node-mean -> partial
    k_gather_mean<<<dim3(NG, 4), 1024, 0, stream>>>(Y2, fillc, epk, degI, b1, partial);

    // K5: head
    k_head<<<NG, 128, 0, stream>>>(partial, Wt, bt, gamma, beta, rmean, rvar, out);

    (void)in_sizes; (void)n_in; (void)out_size; (void)ws_size;
}

// Round 7
// 169.654 us; speedup vs baseline: 1.5307x; 1.5307x over previous
//
#include <hip/hip_runtime.h>
#include <hip/hip_bf16.h>

#define NN 512      // nodes per graph
#define NE 8192     // edges per graph
#define NG 128      // graphs (B*G)
#define FH 128      // feature/hidden dim
#define APITCH 68   // A-chunk float pitch: 272 B row (16B-aligned)
#define XPITCH 136
#define BN_EPS 1e-5f

typedef __attribute__((ext_vector_type(8))) short s8v;            // 8 bf16 = 4 VGPRs
typedef __attribute__((ext_vector_type(4))) float f4v;            // 16x16 MFMA C/D
typedef __attribute__((ext_vector_type(16))) float f16v;          // 32x32 MFMA C/D
typedef __attribute__((ext_vector_type(4))) unsigned short us4v;  // native ushort4
typedef __attribute__((ext_vector_type(4))) unsigned int u4v;

__device__ inline unsigned short f2bf(float x) {   // RNE fp32 -> bf16 bits
    unsigned u = __float_as_uint(x);
    unsigned r = (u + 0x7fffu + ((u >> 16) & 1u)) >> 16;
    return (unsigned short)r;
}
__device__ inline float bf2f(unsigned short h) { return __uint_as_float(((unsigned)h) << 16); }

// pack hi16(f1):hi16(f0) -> one u32 (exact bf16 for integer-valued floats < 256)
__device__ inline unsigned bfpack(int f1bits, int f0bits) {
    return __builtin_amdgcn_perm((unsigned)f1bits, (unsigned)f0bits, 0x07060302u);
}

// Af chunk swizzle: 16B chunk index XOR'd with even value from row bits 3..4
// (spreads the 4 aliasing row classes across banks; even XOR keeps b128 pairs contiguous)
__device__ inline int aswz(int row, int col) {
    return row * APITCH + ((((col >> 2) ^ (((row >> 3) & 3) << 1)) << 2) | (col & 3));
}

// ---------------- K1: degrees + norms + 32-bucket (dst128blk, src64chunk) packed edges;
//                 payload = (d&127)<<6 | (s&63); blocks >= NG pack W ----------------
__global__ __launch_bounds__(1024) void k_build(const int* __restrict__ edges,
                                                float* __restrict__ rs_out,
                                                float* __restrict__ rs_in,
                                                int* __restrict__ bofs,
                                                unsigned short* __restrict__ epk,
                                                const float* __restrict__ W0,
                                                const float* __restrict__ W1,
                                                unsigned short* __restrict__ WP) {
    int g = blockIdx.x;
    int tid = threadIdx.x;

    if (g >= NG) {
        int which = g - NG;
        const float* W = which ? W1 : W0;
        for (int task = tid; task < 2048; task += 1024) {
            int t = task >> 6;            // 0..31  (nt*4+kk)
            int lane = task & 63;
            int nt = t >> 2, kk = t & 3;
            int n = nt * 16 + (lane & 15);
            int k0 = kk * 32 + (lane >> 4) * 8;
            unsigned short* dh = WP + ((size_t)which * 2 + 0) * 16384 + ((size_t)t * 64 + lane) * 8;
            unsigned short* dl = WP + ((size_t)which * 2 + 1) * 16384 + ((size_t)t * 64 + lane) * 8;
#pragma unroll
            for (int j = 0; j < 8; j++) {
                float v = W[(size_t)(k0 + j) * FH + n];
                unsigned short h = f2bf(v);
                dh[j] = h;
                dl[j] = f2bf(v - bf2f(h));
            }
        }
        return;
    }

    const int* src = edges + (size_t)g * 2 * NE;
    const int* dst = src + NE;

    __shared__ int degO[NN], degI[NN];
    __shared__ int scanA[1024], scanB[1024];   // [bucket 32][replica 32] counts / scan ping-pong
    __shared__ int fill[1024];
    __shared__ unsigned short pk[NE];          // 16 KB packed edges

    for (int i = tid; i < NN; i += 1024) { degO[i] = 0; degI[i] = 0; }
    scanA[tid] = 0;
    __syncthreads();

    int rep = tid & 31;
    for (int u = tid; u < NE / 4; u += 1024) {
        int4 s = ((const int4*)src)[u];
        int4 d = ((const int4*)dst)[u];
        atomicAdd(&degO[s.x], 1); atomicAdd(&degO[s.y], 1);
        atomicAdd(&degO[s.z], 1); atomicAdd(&degO[s.w], 1);
        atomicAdd(&degI[d.x], 1); atomicAdd(&degI[d.y], 1);
        atomicAdd(&degI[d.z], 1); atomicAdd(&degI[d.w], 1);
        atomicAdd(&scanA[((((d.x >> 7) << 3) | (s.x >> 6)) << 5) + rep], 1);
        atomicAdd(&scanA[((((d.y >> 7) << 3) | (s.y >> 6)) << 5) + rep], 1);
        atomicAdd(&scanA[((((d.z >> 7) << 3) | (s.z >> 6)) << 5) + rep], 1);
        atomicAdd(&scanA[((((d.w >> 7) << 3) | (s.w >> 6)) << 5) + rep], 1);
    }
    __syncthreads();

    for (int i = tid; i < NN; i += 1024) {
        rs_out[g * NN + i] = rsqrtf((float)max(degO[i], 1));
        rs_in [g * NN + i] = rsqrtf((float)max(degI[i], 1));
    }

    // inclusive Hillis-Steele scan over the 1024 (bucket,replica) cells
    int* sA = scanA; int* sB = scanB;
    for (int off = 1; off < 1024; off <<= 1) {
        int v = sA[tid];
        if (tid >= off) v += sA[tid - off];
        sB[tid] = v;
        __syncthreads();
        int* t = sA; sA = sB; sB = t;
    }
    int excl = tid ? sA[tid - 1] : 0;
    fill[tid] = excl;
    if ((tid & 31) == 0) bofs[g * 33 + (tid >> 5)] = excl;   // bucket start = excl at cell b*32
    if (tid == 0) bofs[g * 33 + 32] = NE;
    __syncthreads();

    for (int u = tid; u < NE / 4; u += 1024) {
        int4 s = ((const int4*)src)[u];
        int4 d = ((const int4*)dst)[u];
        int c, p;
        c = ((((d.x >> 7) << 3) | (s.x >> 6)) << 5) + rep;
        p = atomicAdd(&fill[c], 1); pk[p] = (unsigned short)(((d.x & 127) << 6) | (s.x & 63));
        c = ((((d.y >> 7) << 3) | (s.y >> 6)) << 5) + rep;
        p = atomicAdd(&fill[c], 1); pk[p] = (unsigned short)(((d.y & 127) << 6) | (s.y & 63));
        c = ((((d.z >> 7) << 3) | (s.z >> 6)) << 5) + rep;
        p = atomicAdd(&fill[c], 1); pk[p] = (unsigned short)(((d.z & 127) << 6) | (s.z & 63));
        c = ((((d.w >> 7) << 3) | (s.w >> 6)) << 5) + rep;
        p = atomicAdd(&fill[c], 1); pk[p] = (unsigned short)(((d.w & 127) << 6) | (s.w & 63));
    }
    __syncthreads();
    // 8192 ushorts = 1024 int4, exactly one per thread
    ((int4*)(epk + (size_t)g * NE))[tid] = ((const int4*)pk)[tid];
}

// ---------------- K2: Y1P = pack32((feats @ W0) * rs_out)  (hi/lo split, 3 MFMA) ----------------
// Y1P layout (per graph): idx = ((kb*2 + h)*128 + c)*8 + j holds Y[kb*16 + h*8 + j][c]
__global__ __launch_bounds__(256) void k_gemm_f32(const float* __restrict__ X,
                                                  const unsigned short* __restrict__ WPh,
                                                  const unsigned short* __restrict__ WPl,
                                                  const float* __restrict__ rs,
                                                  unsigned short* __restrict__ Yf) {
    __shared__ unsigned short xh[64 * XPITCH];   // 17 KB
    __shared__ unsigned short xl[64 * XPITCH];   // 17 KB
    int tid = threadIdx.x;
    int sb = blockIdx.y;
    size_t r0 = (size_t)blockIdx.x * NN + (size_t)sb * 64;

    const float4* Xv = (const float4*)(X + r0 * FH);
#pragma unroll
    for (int i = 0; i < 8; i++) {
        int u = tid + i * 256;                 // 2048 float4 = 64x128
        int row = u >> 5, c4 = (u & 31) * 4;
        float4 v = Xv[u];
        int off = row * XPITCH + c4;
        unsigned short h0 = f2bf(v.x), h1 = f2bf(v.y), h2 = f2bf(v.z), h3 = f2bf(v.w);
        us4v hv, lv;
        hv.x = h0; hv.y = h1; hv.z = h2; hv.w = h3;
        lv.x = f2bf(v.x - bf2f(h0));
        lv.y = f2bf(v.y - bf2f(h1));
        lv.z = f2bf(v.z - bf2f(h2));
        lv.w = f2bf(v.w - bf2f(h3));
        *(us4v*)(xh + off) = hv;
        *(us4v*)(xl + off) = lv;
    }
    __syncthreads();

    int lane = tid & 63, w = tid >> 6;
    int quad = lane >> 4, m = lane & 15;
    int arow = w * 16 + m;

    f4v acc[8];
#pragma unroll
    for (int nt = 0; nt < 8; nt++) acc[nt] = (f4v){0.f, 0.f, 0.f, 0.f};

#pragma unroll
    for (int kk = 0; kk < 4; kk++) {
        s8v ah = *(const s8v*)&xh[arow * XPITCH + kk * 32 + quad * 8];
        s8v al = *(const s8v*)&xl[arow * XPITCH + kk * 32 + quad * 8];
#pragma unroll
        for (int nt = 0; nt < 8; nt++) {
            s8v bh = *(const s8v*)(WPh + ((size_t)(nt * 4 + kk) * 64 + lane) * 8);
            s8v bl = *(const s8v*)(WPl + ((size_t)(nt * 4 + kk) * 64 + lane) * 8);
            acc[nt] = __builtin_amdgcn_mfma_f32_16x16x32_bf16(ah, bh, acc[nt], 0, 0, 0);
            acc[nt] = __builtin_amdgcn_mfma_f32_16x16x32_bf16(al, bh, acc[nt], 0, 0, 0);
            acc[nt] = __builtin_amdgcn_mfma_f32_16x16x32_bf16(ah, bl, acc[nt], 0, 0, 0);
        }
    }

    int orow = w * 16 + quad * 4;
    float4 rsv = *(const float4*)(rs + r0 + orow);
    // node n = sb*64 + w*16 + quad*4 + i -> kb = sb*4 + w, h = quad>>1, j = (quad&1)*4 + i
    int kb = sb * 4 + w, h2 = quad >> 1, j0 = (quad & 1) * 4;
    unsigned short* of = Yf + (size_t)blockIdx.x * (NN * FH);
#pragma unroll
    for (int nt = 0; nt < 8; nt++) {
        us4v v;
        v.x = f2bf(acc[nt][0] * rsv.x);
        v.y = f2bf(acc[nt][1] * rsv.y);
        v.z = f2bf(acc[nt][2] * rsv.z);
        v.w = f2bf(acc[nt][3] * rsv.w);
        *(us4v*)(of + ((size_t)(kb * 2 + h2) * 128 + nt * 16 + m) * 8 + j0) = v;
    }
}

// ---------------- K3: dense-A 32x32 MFMA aggregation (32x64/wave, swizzled Af) + gemm2 -> Y2P ----------------
__global__ __launch_bounds__(512) void k_fused(const unsigned short* __restrict__ Y1f,
                                               const int* __restrict__ bofs,
                                               const unsigned short* __restrict__ epk,
                                               const float* __restrict__ rs_in,
                                               const float* __restrict__ rs_out,
                                               const float* __restrict__ bias,
                                               const unsigned short* __restrict__ WPh,
                                               const unsigned short* __restrict__ WPl,
                                               unsigned short* __restrict__ Y2f) {
    int g  = blockIdx.x;
    int sb = blockIdx.y;   // 0..3
    int tid = threadIdx.x;
    int lane = tid & 63, w8 = tid >> 6;    // 8 waves
    int l31 = lane & 31, lh = lane >> 5;
    int mt = w8 & 3, nh = w8 >> 2;         // wave tile: rows mt*32..+31, cols nh*64..+63
    int base = sb * 128;

    __shared__ float Af[128 * APITCH];            // 34816 B; hs aliases this after agg
    __shared__ unsigned short Bs[4 * 2 * 128 * 8]; // 16384 B B-chunk (4 kb x 2 h x 128 c x 8 j)
    unsigned short* hs = (unsigned short*)Af;     // 128*XPITCH*2 = 34816 B exactly
    __shared__ float rsin_s[128];
    __shared__ int bo_s[9];

    const unsigned short* ep = epk + (size_t)g * NE;
    const int4* Yi4 = (const int4*)(Y1f + (size_t)g * (NN * FH));
    int4* Bi4 = (int4*)Bs;

    int4 rB0 = Yi4[tid];
    int4 rB1 = Yi4[tid + 512];

    if (tid < 128) rsin_s[tid] = rs_in[g * NN + base + tid];
    if (tid < 9) bo_s[tid] = bofs[g * 33 + sb * 8 + tid];
    __syncthreads();
    int evNext = -1;
    { int e0 = bo_s[0] + tid; if (e0 < bo_s[1]) evNext = (int)ep[e0]; }

    f16v acc32[2];
#pragma unroll
    for (int t = 0; t < 2; t++)
#pragma unroll
        for (int i = 0; i < 16; i++) acc32[t][i] = 0.f;

    for (int p = 0; p < 8; p++) {
        if (p) __syncthreads();             // prior pass's Af/Bs reads done
        float4 z4 = {0.f, 0.f, 0.f, 0.f};
        for (int i = tid; i < 128 * APITCH / 4; i += 512) ((float4*)Af)[i] = z4;
        Bi4[tid] = rB0;
        Bi4[tid + 512] = rB1;
        __syncthreads();                    // zero + B visible
        if (evNext >= 0)
            atomicAdd(&Af[aswz(evNext >> 6, evNext & 63)], 1.0f);
        for (int e = bo_s[p] + tid + 512; e < bo_s[p + 1]; e += 512) {   // practically never taken
            int v = ep[e];
            atomicAdd(&Af[aswz(v >> 6, v & 63)], 1.0f);
        }
        __syncthreads();                    // A ready
        if (p < 7) {
            rB0 = Yi4[(p + 1) * 1024 + tid];
            rB1 = Yi4[(p + 1) * 1024 + tid + 512];
            int e1 = bo_s[p + 1] + tid;
            evNext = (e1 < bo_s[p + 2]) ? (int)ep[e1] : -1;
        } else evNext = -1;
#pragma unroll
        for (int kk = 0; kk < 4; kk++) {
            s8v bf0 = *(const s8v*)&Bs[(((kk * 2 + lh) * 128) + nh * 64 + l31) * 8];
            s8v bf1 = *(const s8v*)&Bs[(((kk * 2 + lh) * 128) + nh * 64 + 32 + l31) * 8];
            int row = mt * 32 + l31;
            int chunk = (kk * 4 + lh * 2) ^ (((row >> 3) & 3) << 1);
            const int4* ap = (const int4*)&Af[row * APITCH + chunk * 4];
            int4 a0 = ap[0];
            int4 a1 = ap[1];
            union { u4v u; s8v s; } cv;
            cv.u.x = bfpack(a0.y, a0.x);
            cv.u.y = bfpack(a0.w, a0.z);
            cv.u.z = bfpack(a1.y, a1.x);
            cv.u.w = bfpack(a1.w, a1.z);
            acc32[0] = __builtin_amdgcn_mfma_f32_32x32x16_bf16(cv.s, bf0, acc32[0], 0, 0, 0);
            acc32[1] = __builtin_amdgcn_mfma_f32_32x32x16_bf16(cv.s, bf1, acc32[1], 0, 0, 0);
        }
    }
    __syncthreads();   // agg done; Af reusable as hs

    // ---- conv1 epilogue: h = relu(rs_in*agg + b0) -> hs (natural [row][feat]) ----
    // C layout (m74): col = lane&31, row = (reg&3) + 8*(reg>>2) + 4*(lane>>5)
#pragma unroll
    for (int t = 0; t < 2; t++) {
        int c = nh * 64 + t * 32 + l31;
        float bv = bias[c];
#pragma unroll
        for (int r = 0; r < 16; r++) {
            int row = mt * 32 + (r & 3) + 8 * (r >> 2) + 4 * lh;
            float hv = fmaxf(fmaf(rsin_s[row], acc32[t][r], bv), 0.f);
            hs[row * XPITCH + c] = f2bf(hv);
        }
    }
    __syncthreads();

    // ---- gemm2: Y2 = (h @ W1) * rs_out -> Y2P (pack32) ----
    int quad = lane >> 4, m16 = lane & 15;
    f4v acc2[8];
#pragma unroll
    for (int nt = 0; nt < 8; nt++) acc2[nt] = (f4v){0.f, 0.f, 0.f, 0.f};

#pragma unroll
    for (int kk = 0; kk < 4; kk++) {
        s8v ah = *(const s8v*)&hs[(w8 * 16 + m16) * XPITCH + kk * 32 + quad * 8];
#pragma unroll
        for (int nt = 0; nt < 8; nt++) {
            s8v bh = *(const s8v*)(WPh + ((size_t)(nt * 4 + kk) * 64 + lane) * 8);
            s8v bl = *(const s8v*)(WPl + ((size_t)(nt * 4 + kk) * 64 + lane) * 8);
            acc2[nt] = __builtin_amdgcn_mfma_f32_16x16x32_bf16(ah, bh, acc2[nt], 0, 0, 0);
            acc2[nt] = __builtin_amdgcn_mfma_f32_16x16x32_bf16(ah, bl, acc2[nt], 0, 0, 0);
        }
    }

    int orow = w8 * 16 + quad * 4;
    float4 rsv = *(const float4*)(rs_out + (size_t)g * NN + base + orow);
    // node n = base + w8*16 + quad*4 + i -> kb = sb*8 + w8, h = quad>>1, j = (quad&1)*4 + i
    int kb = sb * 8 + w8, h2 = quad >> 1, j0 = (quad & 1) * 4;
    unsigned short* of = Y2f + (size_t)g * (NN * FH);
#pragma unroll
    for (int nt = 0; nt < 8; nt++) {
        us4v v;
        v.x = f2bf(acc2[nt][0] * rsv.x);
        v.y = f2bf(acc2[nt][1] * rsv.y);
        v.z = f2bf(acc2[nt][2] * rsv.z);
        v.w = f2bf(acc2[nt][3] * rsv.w);
        *(us4v*)(of + ((size_t)(kb * 2 + h2) * 128 + nt * 16 + m16) * 8 + j0) = v;
    }
}

// ---------------- K4: dense-A 32x32 MFMA aggregation + relu + node-sum -> partial ----------------
__global__ __launch_bounds__(512) void k_gather_mean(const unsigned short* __restrict__ Y2f,
                                                     const int* __restrict__ bofs,
                                                     const unsigned short* __restrict__ epk,
                                                     const float* __restrict__ rs_in,
                                                     const float* __restrict__ bias,
                                                     float* __restrict__ partial) {
    int g  = blockIdx.x;
    int sb = blockIdx.y;   // 0..3
    int tid = threadIdx.x;
    int lane = tid & 63, w8 = tid >> 6;
    int l31 = lane & 31, lh = lane >> 5;
    int mt = w8 & 3, nh = w8 >> 2;
    int base = sb * 128;

    __shared__ float Af[128 * APITCH];            // 34816 B; red aliases this after agg
    __shared__ unsigned short Bs[4 * 2 * 128 * 8]; // 16384 B
    float* red = (float*)Af;                      // [8][2][64] = 4096 B
    __shared__ float rsin_s[128];
    __shared__ int bo_s[9];

    const unsigned short* ep = epk + (size_t)g * NE;
    const int4* Yi4 = (const int4*)(Y2f + (size_t)g * (NN * FH));
    int4* Bi4 = (int4*)Bs;

    int4 rB0 = Yi4[tid];
    int4 rB1 = Yi4[tid + 512];

    if (tid < 128) rsin_s[tid] = rs_in[g * NN + base + tid];
    if (tid < 9) bo_s[tid] = bofs[g * 33 + sb * 8 + tid];
    __syncthreads();
    int evNext = -1;
    { int e0 = bo_s[0] + tid; if (e0 < bo_s[1]) evNext = (int)ep[e0]; }

    f16v acc32[2];
#pragma unroll
    for (int t = 0; t < 2; t++)
#pragma unroll
        for (int i = 0; i < 16; i++) acc32[t][i] = 0.f;

    for (int p = 0; p < 8; p++) {
        if (p) __syncthreads();
        float4 z4 = {0.f, 0.f, 0.f, 0.f};
        for (int i = tid; i < 128 * APITCH / 4; i += 512) ((float4*)Af)[i] = z4;
        Bi4[tid] = rB0;
        Bi4[tid + 512] = rB1;
        __syncthreads();
        if (evNext >= 0)
            atomicAdd(&Af[aswz(evNext >> 6, evNext & 63)], 1.0f);
        for (int e = bo_s[p] + tid + 512; e < bo_s[p + 1]; e += 512) {
            int v = ep[e];
            atomicAdd(&Af[aswz(v >> 6, v & 63)], 1.0f);
        }
        __syncthreads();
        if (p < 7) {
            rB0 = Yi4[(p + 1) * 1024 + tid];
            rB1 = Yi4[(p + 1) * 1024 + tid + 512];
            int e1 = bo_s[p + 1] + tid;
            evNext = (e1 < bo_s[p + 2]) ? (int)ep[e1] : -1;
        } else evNext = -1;
#pragma unroll
        for (int kk = 0; kk < 4; kk++) {
            s8v bf0 = *(const s8v*)&Bs[(((kk * 2 + lh) * 128) + nh * 64 + l31) * 8];
            s8v bf1 = *(const s8v*)&Bs[(((kk * 2 + lh) * 128) + nh * 64 + 32 + l31) * 8];
            int row = mt * 32 + l31;
            int chunk = (kk * 4 + lh * 2) ^ (((row >> 3) & 3) << 1);
            const int4* ap = (const int4*)&Af[row * APITCH + chunk * 4];
            int4 a0 = ap[0];
            int4 a1 = ap[1];
            union { u4v u; s8v s; } cv;
            cv.u.x = bfpack(a0.y, a0.x);
            cv.u.y = bfpack(a0.w, a0.z);
            cv.u.z = bfpack(a1.y, a1.x);
            cv.u.w = bfpack(a1.w, a1.z);
            acc32[0] = __builtin_amdgcn_mfma_f32_32x32x16_bf16(cv.s, bf0, acc32[0], 0, 0, 0);
            acc32[1] = __builtin_amdgcn_mfma_f32_32x32x16_bf16(cv.s, bf1, acc32[1], 0, 0, 0);
        }
    }
    __syncthreads();   // agg done; Af reusable as red

    // ---- epilogue: relu(rs_in*agg + b1) summed over this lane's rows, per col ----
#pragma unroll
    for (int t = 0; t < 2; t++) {
        int c = nh * 64 + t * 32 + l31;
        float bv = bias[c];
        float s = 0.f;
#pragma unroll
        for (int r = 0; r < 16; r++) {
            int row = mt * 32 + (r & 3) + 8 * (r >> 2) + 4 * lh;
            s += fmaxf(fmaf(rsin_s[row], acc32[t][r], bv), 0.f);
        }
        red[(w8 * 2 + t) * 64 + lane] = s;
    }
    __syncthreads();
    if (tid < FH) {
        int f = tid;
        int nh2 = f >> 6, t2 = (f >> 5) & 1, cl = f & 31;
        float t = 0.f;
#pragma unroll
        for (int mtt = 0; mtt < 4; mtt++) {
            int w = nh2 * 4 + mtt;
            t += red[(w * 2 + t2) * 64 + cl] + red[(w * 2 + t2) * 64 + cl + 32];
        }
        partial[((size_t)g * 4 + sb) * FH + f] = t;
    }
}

// ---------------- K5: z = (sum partials)/512 @ Wt + bt; BN eval; relu ----------------
__global__ __launch_bounds__(128) void k_head(const float* __restrict__ partial,
                                              const float* __restrict__ Wt,
                                              const float* __restrict__ bt,
                                              const float* __restrict__ gamma,
                                              const float* __restrict__ beta,
                                              const float* __restrict__ rmean,
                                              const float* __restrict__ rvar,
                                              float* __restrict__ out) {
    int g = blockIdx.x;
    int j = threadIdx.x;
    __shared__ float e[FH];
    float acc4 = 0.f;
#pragma unroll
    for (int q = 0; q < 4; q++) acc4 += partial[((size_t)g * 4 + q) * FH + j];
    e[j] = acc4 * (1.0f / (float)NN);
    __syncthreads();
    float acc = bt[j];
#pragma unroll 8
    for (int k = 0; k < FH; k++) acc += e[k] * Wt[(size_t)k * FH + j];
    float z = gamma[j] * (acc - rmean[j]) * rsqrtf(rvar[j] + BN_EPS) + beta[j];
    out[g * FH + j] = fmaxf(z, 0.f);
}

extern "C" void kernel_launch(void* const* d_in, const int* in_sizes, int n_in,
                              void* d_out, int out_size, void* d_ws, size_t ws_size,
                              hipStream_t stream) {
    const float* feats = (const float*)d_in[0];
    const int*   edges = (const int*)d_in[1];
    const float* W0    = (const float*)d_in[2];
    const float* b0    = (const float*)d_in[3];
    const float* W1    = (const float*)d_in[4];
    const float* b1    = (const float*)d_in[5];
    const float* Wt    = (const float*)d_in[6];
    const float* bt    = (const float*)d_in[7];
    const float* gamma = (const float*)d_in[8];
    const float* beta  = (const float*)d_in[9];
    const float* rmean = (const float*)d_in[10];
    const float* rvar  = (const float*)d_in[11];
    float* out = (float*)d_out;

    // workspace layout
    char* w = (char*)d_ws;
    float* rs_out  = (float*)w;   w += sizeof(float) * NG * NN;
    float* rs_in   = (float*)w;   w += sizeof(float) * NG * NN;
    int*   bofs    = (int*)w;     w += sizeof(int) * NG * 33;              // 16896 B (16B multiple)
    unsigned short* epk = (unsigned short*)w; w += sizeof(unsigned short) * (size_t)NG * NE; // 2 MB
    unsigned short* WP  = (unsigned short*)w; w += sizeof(unsigned short) * 4 * 16384;       // 128 KB
    unsigned short* Y1  = (unsigned short*)w; w += sizeof(unsigned short) * (size_t)NG * NN * FH; // 16 MB
    unsigned short* Y2  = (unsigned short*)w; w += sizeof(unsigned short) * (size_t)NG * NN * FH; // 16 MB
    float* partial = (float*)w;   w += sizeof(float) * NG * 4 * FH;

    unsigned short* WPh0 = WP;
    unsigned short* WPl0 = WP + 16384;
    unsigned short* WPh1 = WP + 32768;
    unsigned short* WPl1 = WP + 49152;

    // K1: norms + bucketed packed edges; 2 extra blocks pack W0/W1
    k_build<<<NG + 2, 1024, 0, stream>>>(edges, rs_out, rs_in, bofs, epk, W0, W1, WP);

    // K2: conv1 gemm (feats -> Y1, pack32 format)
    k_gemm_f32<<<dim3(NG, 8), 256, 0, stream>>>(feats, WPh0, WPl0, rs_out, Y1);

    // K3: dense-A 32x32 MFMA aggregation + conv2 gemm (Y1 -> Y2, pack32)
    k_fused<<<dim3(NG, 4), 512, 0, stream>>>(Y1, bofs, epk, rs_in, rs_out, b0, WPh1, WPl1, Y2);

    // K4: dense-A 32x32 MFMA aggregation (conv2) + node-mean -> partial
    k_gather_mean<<<dim3(NG, 4), 512, 0, stream>>>(Y2, bofs, epk, rs_in, b1, partial);

    // K5: head
    k_head<<<NG, 128, 0, stream>>>(partial, Wt, bt, gamma, beta, rmean, rvar, out);

    (void)in_sizes; (void)n_in; (void)out_size; (void)ws_size;
}